// Round 13
// baseline (434.623 us; speedup 1.0000x reference)
//
#include <hip/hip_runtime.h>
#include <cstdint>
#include <cstddef>

#define BETA 5.5f
#define ALPHA 0.5f

constexpr int D   = 512;     // feature dim
constexpr int NB  = 4096;    // queries
constexpr int NK  = 16384;   // keys
constexpr int BQ  = 32;      // query tile per block
constexpr int BN  = 32;      // key chunk
constexpr int NSPLIT = 8;    // nsplit = blockIdx&7 ~ XCD id
constexpr int NRANGE = NK / NSPLIT;   // 2048
constexpr int CHUNKS = NRANGE / BN;   // 64
constexpr int KROW = D + 8;           // padded K row (bf16): 1040 B
constexpr int PROW = BN + 8;          // padded P row: 40

typedef __attribute__((ext_vector_type(8)))  short    short8;
typedef __attribute__((ext_vector_type(4)))  float    floatx4;
typedef __attribute__((ext_vector_type(4)))  uint32_t uint4v;
typedef __attribute__((ext_vector_type(2)))  uint32_t uint2v;

__device__ inline uint32_t f2bf1(float f) {
  union { float f; uint32_t u; } v; v.f = f;
  return (v.u + 0x7FFFu + ((v.u >> 16) & 1u)) >> 16;   // RNE
}
__device__ inline uint32_t pack2(float a, float b) {
  return f2bf1(a) | (f2bf1(b) << 16);
}

__device__ inline void load_lds16(const void* g, void* l) {
  __builtin_amdgcn_global_load_lds(
      (const __attribute__((address_space(1))) uint32_t*)g,
      (__attribute__((address_space(3))) uint32_t*)l, 16, 0, 0);
}

// ---- merged: blocks 0..255 normalize K -> Kn + KnT; 256.. normalize Q ------
__global__ void norm_qk_kernel(const float* __restrict__ q,
                               const float* __restrict__ k,
                               float* __restrict__ out,
                               unsigned short* __restrict__ Qn,
                               unsigned short* __restrict__ Kn,
                               unsigned short* __restrict__ KnT) {
  __shared__ unsigned short tile[64 * KROW];
  const int wave = threadIdx.x >> 6, lane = threadIdx.x & 63;

  if (blockIdx.x >= 256) {               // ---- Q path ----
    const int row = (blockIdx.x - 256) * 4 + wave;
    const float4* qr = (const float4*)(q + (size_t)row * D);
    float4 a = qr[lane * 2];
    float4 b = qr[lane * 2 + 1];
    float ss = a.x*a.x + a.y*a.y + a.z*a.z + a.w*a.w
             + b.x*b.x + b.y*b.y + b.z*b.z + b.w*b.w;
#pragma unroll
    for (int m = 32; m >= 1; m >>= 1) ss += __shfl_xor(ss, m, 64);
    const float sc = 1.0f / fmaxf(sqrtf(ss), 1e-12f);
    float4* orow = (float4*)(out + (size_t)row * D);
    orow[lane * 2]     = a;
    orow[lane * 2 + 1] = b;
    uint4v w;
    w.x = pack2(a.x*sc, a.y*sc); w.y = pack2(a.z*sc, a.w*sc);
    w.z = pack2(b.x*sc, b.y*sc); w.w = pack2(b.z*sc, b.w*sc);
    *(uint4v*)(Qn + (size_t)row * D + lane * 8) = w;
    return;
  }
  // ---- K path ----
  const int n0 = blockIdx.x * 64;
#pragma unroll 1
  for (int i = 0; i < 16; ++i) {
    const int rl = wave * 16 + i;
    const int n  = n0 + rl;
    const float4* kr = (const float4*)(k + (size_t)n * D);
    float4 a = kr[lane * 2], b = kr[lane * 2 + 1];
    float ss = a.x*a.x + a.y*a.y + a.z*a.z + a.w*a.w
             + b.x*b.x + b.y*b.y + b.z*b.z + b.w*b.w;
#pragma unroll
    for (int m = 32; m >= 1; m >>= 1) ss += __shfl_xor(ss, m, 64);
    const float sc = 1.0f / fmaxf(sqrtf(ss), 1e-12f);
    uint4v w;
    w.x = pack2(a.x*sc, a.y*sc); w.y = pack2(a.z*sc, a.w*sc);
    w.z = pack2(b.x*sc, b.y*sc); w.w = pack2(b.z*sc, b.w*sc);
    *(uint4v*)(Kn + (size_t)n * D + lane * 8) = w;
    *(uint4v*)&tile[rl * KROW + lane * 8]     = w;
  }
  __syncthreads();
  const int dsub = threadIdx.x >> 3;        // 0..31
  const int nl   = (threadIdx.x & 7) * 8;   // 0..56
#pragma unroll 1
  for (int iter = 0; iter < 16; ++iter) {
    const int d = iter * 32 + dsub;
    uint4v w;
    w.x = (uint32_t)tile[(nl+0)*KROW + d] | ((uint32_t)tile[(nl+1)*KROW + d] << 16);
    w.y = (uint32_t)tile[(nl+2)*KROW + d] | ((uint32_t)tile[(nl+3)*KROW + d] << 16);
    w.z = (uint32_t)tile[(nl+4)*KROW + d] | ((uint32_t)tile[(nl+5)*KROW + d] << 16);
    w.w = (uint32_t)tile[(nl+6)*KROW + d] | ((uint32_t)tile[(nl+7)*KROW + d] << 16);
    *(uint4v*)(KnT + (size_t)d * NK + n0 + nl) = w;
  }
}

// ---------------- fused: S = Qn Kn^T chunk, P = exp, O += P Kn --------------
// R10's verified single-barrier cross-chunk pipeline, scaled to 4-wave blocks
// (BQ=32, BN=32, LDS 70KB, ~200 regs) -> TWO independent blocks per CU.
// Same 8 waves/CU as R10, but two barrier domains: one block's barrier/L2
// stalls are covered by the other block's MFMA/LDS work (the m97/m114 recipe).
// Wave roles: qt = q-16-group, nt = key-16-group; full D per wave (no Sred).
__global__ __launch_bounds__(256, 2) void fused_kernel(
    const unsigned short* __restrict__ Qn,
    const unsigned short* __restrict__ Kn,
    const unsigned short* __restrict__ KnT,
    float* __restrict__ out) {
  __shared__ unsigned short K_lds[2][BN * KROW];   // 2 x 33.3 KB
  __shared__ unsigned short P_lds[2][BQ * PROW];   // 2 x 2.56 KB  (= 70 KB)

  const int tid  = threadIdx.x;
  const int wave = tid >> 6, lane = tid & 63;
  const int l15  = lane & 15, quad = lane >> 4;
  const int nsplit = blockIdx.x & (NSPLIT - 1);
  const int qidx   = blockIdx.x >> 3;           // 0..127
  const int q0     = qidx * BQ;
  const int nbase  = nsplit * NRANGE;
  const int qt = wave & 1, nt = wave >> 1;
  const int dbase = wave * 128;                 // wave's 128 d-cols for GEMM2

  // GEMM1 B-frags (Q): wave's q-16-group, full D (64 VGPR)
  short8 qf[16];
  {
    const unsigned short* qrow = Qn + (size_t)(q0 + qt*16 + l15) * D + quad * 8;
#pragma unroll
    for (int kb = 0; kb < 16; ++kb) qf[kb] = *(const short8*)(qrow + kb * 32);
  }

  floatx4 oacc[2][8] = {};   // O slice: 32q (2 tr) x 128d (8 td) = 64 AGPR
  short8  ktf[8];            // GEMM2 B-frags for wave's 128 d (32 VGPR)

  auto stage = [&](int ch, int buf) {
#pragma unroll
    for (int i = 0; i < 8; ++i) {
      const int row = wave * 8 + i;
      load_lds16(Kn + (size_t)(nbase + ch*BN + row) * D + lane * 8,
                 &K_lds[buf][row * KROW]);
    }
  };
  auto ktf_load = [&](int ch) {
#pragma unroll
    for (int td = 0; td < 8; ++td)
      ktf[td] = *(const short8*)(KnT + (size_t)(dbase + td*16 + l15) * NK
                                 + (nbase + ch*BN + quad*8));
  };
  auto gemm1_half = [&](int buf, int kb0, floatx4& s) {
#pragma unroll
    for (int kb = kb0; kb < kb0 + 8; ++kb) {
      short8 a = *(const short8*)&K_lds[buf][(nt*16 + l15) * KROW + kb*32 + quad*8];
      s = __builtin_amdgcn_mfma_f32_16x16x32_bf16(a, qf[kb], s, 0, 0, 0);
    }
  };
  auto exp_pw = [&](int buf, const floatx4& s) {
    // C/D: col=l15 (q), rows (keys) = quad*4 + r
    uint2v w;
    w.x = pack2(__expf(BETA * (s[0] - 1.f)), __expf(BETA * (s[1] - 1.f)));
    w.y = pack2(__expf(BETA * (s[2] - 1.f)), __expf(BETA * (s[3] - 1.f)));
    *(uint2v*)&P_lds[buf][(qt*16 + l15) * PROW + nt*16 + quad*4] = w;
  };
  auto gemm2_half = [&](int buf, int td0) {
#pragma unroll
    for (int tr = 0; tr < 2; ++tr) {
      short8 pf = *(const short8*)&P_lds[buf][(tr*16 + l15) * PROW + quad*8];
#pragma unroll
      for (int td = td0; td < td0 + 4; ++td)
        oacc[tr][td] = __builtin_amdgcn_mfma_f32_16x16x32_bf16(
            pf, ktf[td], oacc[tr][td], 0, 0, 0);
    }
  };

  // ---- prologue
  stage(0, 0);
  ktf_load(0);
  __syncthreads();                       // staging(0) drained
  {
    stage(1, 1);
    floatx4 s = {};
    gemm1_half(0, 0, s);
    gemm1_half(0, 8, s);
    exp_pw(0, s);
  }
  __syncthreads();                       // P(0) visible; staging(1) drained

  // ---- steady: region c = {stage(c+2); GEMM2(c) x GEMM1(c+1) interleaved;
  //                          ktf(c+1); exp->P(c+1)}; ONE barrier
#pragma unroll 1
  for (int c = 0; c < CHUNKS; ++c) {
    const int cur = c & 1, nxt = cur ^ 1;
    if (c + 2 < CHUNKS) stage(c + 2, cur);   // K_lds[cur] last read region c-1
    floatx4 s = {};
    gemm2_half(cur, 0);                      // GEMM2(c) first half (uses ktf)
    if (c + 1 < CHUNKS) gemm1_half(nxt, 0, s);
    gemm2_half(cur, 4);                      // GEMM2(c) second half
    if (c + 1 < CHUNKS) {
      gemm1_half(nxt, 8, s);
      ktf_load(c + 1);                       // after gemm2 consumed ktf(c)
      exp_pw(nxt, s);
    }
    __syncthreads();                         // P(c+1) visible; stage/ktf drained
  }

  // ---- epilogue: out += ALPHA * O (out pre-init to Q; atomics L2-coalesce)
#pragma unroll
  for (int tr = 0; tr < 2; ++tr)
#pragma unroll
    for (int td = 0; td < 8; ++td)
#pragma unroll
      for (int r = 0; r < 4; ++r)
        atomicAdd(out + (size_t)(q0 + tr*16 + quad*4 + r) * D
                      + dbase + td*16 + l15,
                  ALPHA * oacc[tr][td][r]);
}

extern "C" void kernel_launch(void* const* d_in, const int* in_sizes, int n_in,
                              void* d_out, int out_size, void* d_ws, size_t ws_size,
                              hipStream_t stream) {
  (void)in_sizes; (void)n_in; (void)out_size; (void)ws_size;
  const float* q = (const float*)d_in[0];
  const float* k = (const float*)d_in[1];
  float* out = (float*)d_out;
  unsigned short* Qn  = (unsigned short*)d_ws;          //  4 MB
  unsigned short* Kn  = Qn + (size_t)NB * D;            // 16 MB
  unsigned short* KnT = Kn + (size_t)NK * D;            // 16 MB  (total 36 MB)

  hipLaunchKernelGGL(norm_qk_kernel, dim3(256 + NB / 4), dim3(256), 0, stream,
                     q, k, out, Qn, Kn, KnT);
  hipLaunchKernelGGL(fused_kernel, dim3((NB / BQ) * NSPLIT), dim3(256), 0, stream,
                     Qn, Kn, KnT, out);
}